// Round 8
// baseline (283.215 us; speedup 1.0000x reference)
//
#include <hip/hip_runtime.h>
#include <hip/hip_bf16.h>
#include <hip/hip_fp16.h>

#define N_NODES 32768
#define E_EDGES 524288
#define HIDDIM 128
#define FDIM 512
#define DFF 2048
#define LN_EPS 1e-5f
#define SLOPE 0.2f
#define CAP 64          // CSR slot capacity per dst (Poisson(16): P(>64) ~ 1e-19)

typedef __bf16 bf16_t;
typedef __bf16 bf16x8 __attribute__((ext_vector_type(8)));
typedef float f32x4 __attribute__((ext_vector_type(4)));
typedef float f32x2 __attribute__((ext_vector_type(2)));

#define GLD_LDS16(gp, lp) __builtin_amdgcn_global_load_lds( \
    (const __attribute__((address_space(1))) unsigned int*)(gp), \
    (__attribute__((address_space(3))) unsigned int*)(lp), 16, 0, 0)

// ---------- fp8 e4m3 codec (HW cvt when available) ----------
__device__ inline unsigned char f32_to_e4m3(float v) {
#if __has_builtin(__builtin_amdgcn_cvt_pk_fp8_f32)
    return (unsigned char)(__builtin_amdgcn_cvt_pk_fp8_f32(v, v, 0, false) & 0xff);
#else
    unsigned bits = __float_as_uint(v);
    unsigned sign = (bits >> 24) & 0x80;
    float av = fabsf(v);
    if (av >= 448.f) return (unsigned char)(sign | 0x7E);
    int e = (int)((bits >> 23) & 0xFF) - 127;
    if (e < -6) { int n = (int)rintf(av * 512.f); return (unsigned char)(sign | n); }
    float ulp = exp2f((float)(e - 3));
    int n = (int)rintf(av / ulp);
    if (n == 16) { e += 1; n = 8; }
    return (unsigned char)(sign | ((e + 7) << 3) | (n - 8));
#endif
}
template<bool HI>
__device__ inline f32x2 e4m3x2_to_f32(unsigned u) {
#if __has_builtin(__builtin_amdgcn_cvt_pk_f32_fp8)
    return __builtin_amdgcn_cvt_pk_f32_fp8(u, HI);
#else
    f32x2 r;
    unsigned b0 = HI ? ((u >> 16) & 0xff) : (u & 0xff);
    unsigned b1 = HI ? ((u >> 24) & 0xff) : ((u >> 8) & 0xff);
    unsigned bs[2] = {b0, b1};
    for (int i = 0; i < 2; ++i) {
        unsigned b = bs[i];
        float s = (b & 0x80) ? -1.f : 1.f;
        int e = (b >> 3) & 15, m = b & 7;
        float v = e ? (8 + m) * exp2f((float)(e - 10)) : m * exp2f(-9.f);
        r[i] = s * v;
    }
    return r;
#endif
}

// ============ prep: h->bf16, all weight k8-packs, ce — one dispatch ============
__device__ inline void pack_range(const float* __restrict__ B, bf16_t* __restrict__ out,
                                  int id, int N) {
    const int g = id / N, n = id % N;
    union { bf16_t b[8]; uint4 u; } pk;
#pragma unroll
    for (int j = 0; j < 8; ++j) pk.b[j] = (bf16_t)B[(size_t)(g * 8 + j) * N + n];
    *(uint4*)(out + (size_t)id * 8) = pk.u;
}

__global__ __launch_bounds__(256) void prep_kernel(const float* __restrict__ h, bf16_t* __restrict__ hb,
                                                   const float* __restrict__ W_fc, bf16_t* __restrict__ Wfc_p,
                                                   const float* __restrict__ W_res, bf16_t* __restrict__ Wres_p,
                                                   const float* __restrict__ W_mha, bf16_t* __restrict__ Wmha_p,
                                                   const float* __restrict__ W1, bf16_t* __restrict__ W1_p,
                                                   const float* __restrict__ W2, bf16_t* __restrict__ W2_p,
                                                   const float* __restrict__ W_fe, const float* __restrict__ attn_e,
                                                   float* __restrict__ ce) {
    int bid = blockIdx.x;
    const int tid = threadIdx.x;
    if (bid < 4096) {                       // h fp32 -> bf16 (4 elems/thread)
        const int id = bid * 256 + tid;
        const float4 v = ((const float4*)h)[id];
        union { bf16_t b[4]; uint2 u; } pk;
        pk.b[0] = (bf16_t)v.x; pk.b[1] = (bf16_t)v.y; pk.b[2] = (bf16_t)v.z; pk.b[3] = (bf16_t)v.w;
        *(uint2*)(hb + (size_t)id * 4) = pk.u;
        return;
    }
    bid -= 4096;
    if (bid < 32)  { pack_range(W_fc,  Wfc_p,  bid * 256 + tid, 512);  return; }
    bid -= 32;
    if (bid < 32)  { pack_range(W_res, Wres_p, bid * 256 + tid, 512);  return; }
    bid -= 32;
    if (bid < 32)  { pack_range(W_mha, Wmha_p, bid * 256 + tid, 128);  return; }
    bid -= 32;
    if (bid < 128) { pack_range(W1,    W1_p,   bid * 256 + tid, 2048); return; }
    bid -= 128;
    if (bid < 128) { pack_range(W2,    W2_p,   bid * 256 + tid, 128);  return; }
    // ce
    if (tid < 128) {
        const float4 w = ((const float4*)W_fe)[tid];
        const float4 a = ((const float4*)attn_e)[tid];
        float p = w.x * a.x + w.y * a.y + w.z * a.z + w.w * a.w;
        for (int off = 16; off; off >>= 1) p += __shfl_down(p, off, 32);
        if ((tid & 31) == 0) ce[tid >> 5] = p;
    }
}

// ============ fused ft+res GEMM: shared A panel (hb), two B matrices ============
__global__ __launch_bounds__(256, 2) void gemm_ftres(const bf16_t* __restrict__ A,
                                                     const bf16_t* __restrict__ Bf,
                                                     const bf16_t* __restrict__ Brs,
                                                     const float* __restrict__ attn_l,
                                                     const float* __restrict__ attn_r,
                                                     unsigned char* __restrict__ ft8,
                                                     float* __restrict__ el,
                                                     float* __restrict__ er,
                                                     bf16_t* __restrict__ res) {
    __shared__ __align__(16) bf16_t lA[4096];
    __shared__ __align__(16) bf16_t lBf[4096];
    __shared__ __align__(16) bf16_t lBr[4096];
    __shared__ float s_el[2][128], s_er[2][128];
    const int tid = threadIdx.x, lane = tid & 63, wave = tid >> 6;
    const int wm = (wave >> 1) * 64, wn = (wave & 1) * 64;
    const int row0 = blockIdx.y * 128;
    const int head = blockIdx.x, col0 = head * 128;
    const int ko = lane >> 4, rl = lane & 15;
    f32x4 accf[4][4] = {};
    f32x4 accr[4][4] = {};
    const int c0 = tid, c1 = tid + 256;
    const int g0 = c0 >> 7, m0 = c0 & 127;
    const int g1 = c1 >> 7, m1 = c1 & 127;
    for (int k0 = 0; k0 < 128; k0 += 32) {
        __syncthreads();
        GLD_LDS16(A + (size_t)(row0 + m0) * 128 + k0 + g0 * 8, lA + c0 * 8);
        GLD_LDS16(A + (size_t)(row0 + m1) * 128 + k0 + g1 * 8, lA + c1 * 8);
        GLD_LDS16(Bf + ((size_t)(k0 / 8 + g0) * 512 + col0 + m0) * 8, lBf + c0 * 8);
        GLD_LDS16(Bf + ((size_t)(k0 / 8 + g1) * 512 + col0 + m1) * 8, lBf + c1 * 8);
        GLD_LDS16(Brs + ((size_t)(k0 / 8 + g0) * 512 + col0 + m0) * 8, lBr + c0 * 8);
        GLD_LDS16(Brs + ((size_t)(k0 / 8 + g1) * 512 + col0 + m1) * 8, lBr + c1 * 8);
        __syncthreads();
        bf16x8 af[4], bff[4], bfr[4];
#pragma unroll
        for (int i = 0; i < 4; ++i) {
            af[i]  = *(const bf16x8*)&lA[(ko * 128 + wm + i * 16 + rl) * 8];
            bff[i] = *(const bf16x8*)&lBf[(ko * 128 + wn + i * 16 + rl) * 8];
            bfr[i] = *(const bf16x8*)&lBr[(ko * 128 + wn + i * 16 + rl) * 8];
        }
#pragma unroll
        for (int i = 0; i < 4; ++i)
#pragma unroll
            for (int j = 0; j < 4; ++j) {
                accf[i][j] = __builtin_amdgcn_mfma_f32_16x16x32_bf16(af[i], bff[j], accf[i][j], 0, 0, 0);
                accr[i][j] = __builtin_amdgcn_mfma_f32_16x16x32_bf16(af[i], bfr[j], accr[i][j], 0, 0, 0);
            }
    }
    const int cr = (lane >> 4) * 4, cc = lane & 15;
    float al[4], ar[4];
#pragma unroll
    for (int j = 0; j < 4; ++j) {
        al[j] = attn_l[col0 + wn + j * 16 + cc];
        ar[j] = attn_r[col0 + wn + j * 16 + cc];
    }
#pragma unroll
    for (int i = 0; i < 4; ++i)
#pragma unroll
        for (int r = 0; r < 4; ++r) {
            const int row = row0 + wm + i * 16 + cr + r;
            float pel = 0.f, per = 0.f;
#pragma unroll
            for (int j = 0; j < 4; ++j) {
                const int col = col0 + wn + j * 16 + cc;
                const float v = accf[i][j][r];
                ft8[(size_t)row * 512 + col] = f32_to_e4m3(v);
                res[(size_t)row * 512 + col] = (bf16_t)accr[i][j][r];
                pel += v * al[j];
                per += v * ar[j];
            }
#pragma unroll
            for (int m = 1; m < 16; m <<= 1) {
                pel += __shfl_xor(pel, m);
                per += __shfl_xor(per, m);
            }
            if (cc == 0) {
                s_el[wn >> 6][wm + i * 16 + cr + r] = pel;
                s_er[wn >> 6][wm + i * 16 + cr + r] = per;
            }
        }
    __syncthreads();
    if (tid < 128) {
        el[(size_t)(row0 + tid) * 4 + head] = s_el[0][tid] + s_el[1][tid];
        er[(size_t)(row0 + tid) * 4 + head] = s_er[0][tid] + s_er[1][tid];
    }
}

// ============ ffn_mega: mha GEMM + LN1 + FFN + LN2 in one kernel ============
// Phase 0 (new): x3 = LN1(h0 + relu(x1 @ Wmha + b_mha)) computed in the prologue —
// the standalone gemm_mha_ln pass (56MB memory-bound) disappears; its traffic hides
// under this kernel's MFMA/LDS-bound phases (HBM was at 6% util). x3 panel lands in
// lX (k8-pack LDS) for the afx lift + stashed to x3b (same-block L2) for the LN2
// residual. Main loop = v7 K-split schedule, unchanged.
__global__ __launch_bounds__(512, 2) void ffn_mega(const bf16_t* __restrict__ x1,
                                                   const bf16_t* __restrict__ Wm,
                                                   const float* __restrict__ b_mha,
                                                   const float* __restrict__ h0,
                                                   const float* __restrict__ n1g,
                                                   const float* __restrict__ n1b,
                                                   bf16_t* __restrict__ x3stash,
                                                   const bf16_t* __restrict__ W1p,
                                                   const float* __restrict__ b1,
                                                   const bf16_t* __restrict__ W2p,
                                                   const float* __restrict__ b2,
                                                   const float* __restrict__ gamma,
                                                   const float* __restrict__ beta,
                                                   float* __restrict__ out) {
    __shared__ __align__(16) bf16_t lW1[3][8192];   // [buf][g16][64][8]; [0..1] doubles as x3 (lX)
    __shared__ __align__(16) bf16_t lW2[4][8192];   // [buf][g8][128][8]
    __shared__ __align__(16) bf16_t lY[2][8192];    // [par][dff>>3][128][8]; phase-0 staging scratch
    __shared__ float s_s1[2][128], s_s2[2][128], s_mu[128], s_rs[128];
    const int tid = threadIdx.x, lane = tid & 63, wave = tid >> 6;
    const int kh  = wave & 1;          // GEMM2 K-half
    const int ds  = wave & 3;          // GEMM1 dff slice (16 wide)
    const int cg  = (wave >> 1) & 1;   // GEMM2 col group (64 wide)
    const int rg  = wave >> 2;         // row group (64 rows)
    const int wr  = rg * 64;
    const int wc1 = ds * 16;
    const int wc2 = cg * 64;
    const int row0 = blockIdx.x * 128;
    const int ko = lane >> 4, rl = lane & 15;
    const int cr = ko * 4, cc = rl;

    // ---- phase 0: mha GEMM 128x128 K=512 + LN1 -> x3 (LDS k8-pack + HBM stash) ----
    {
        const int rg2 = wave >> 1;      // 4 row-groups x 32 rows
        const int cg2 = wave & 1;       // 2 col-groups x 64 cols
        bf16_t* lA = &lY[0][0];         // 8KB  [g4][128rows][8]
        bf16_t* lB = &lY[0][4096];      // 8KB  [g4][128cols][8]
        f32x4 am[2][4] = {};
        for (int k0 = 0; k0 < 512; k0 += 32) {
            __syncthreads();
            {
                const int g = tid >> 7, m = tid & 127;
                GLD_LDS16(x1 + (size_t)(row0 + m) * 512 + k0 + g * 8, lA + tid * 8);
                GLD_LDS16(Wm + ((size_t)(k0 / 8 + g) * 128 + m) * 8, lB + tid * 8);
            }
            __syncthreads();
            bf16x8 af[2], bf[4];
#pragma unroll
            for (int i = 0; i < 2; ++i)
                af[i] = *(const bf16x8*)&lA[(ko * 128 + rg2 * 32 + i * 16 + rl) * 8];
#pragma unroll
            for (int j = 0; j < 4; ++j)
                bf[j] = *(const bf16x8*)&lB[(ko * 128 + cg2 * 64 + j * 16 + rl) * 8];
#pragma unroll
            for (int i = 0; i < 2; ++i)
#pragma unroll
                for (int j = 0; j < 4; ++j)
                    am[i][j] = __builtin_amdgcn_mfma_f32_16x16x32_bf16(af[i], bf[j], am[i][j], 0, 0, 0);
        }
        // bias + relu + h0 residual
#pragma unroll
        for (int j = 0; j < 4; ++j) {
            const int col = cg2 * 64 + j * 16 + cc;
            const float bb = b_mha[col];
#pragma unroll
            for (int i = 0; i < 2; ++i)
#pragma unroll
                for (int r = 0; r < 4; ++r) {
                    const int row = row0 + rg2 * 32 + i * 16 + cr + r;
                    am[i][j][r] = fmaxf(am[i][j][r] + bb, 0.f) + h0[(size_t)row * 128 + col];
                }
        }
        // LN1 stats
#pragma unroll
        for (int i = 0; i < 2; ++i)
#pragma unroll
            for (int r = 0; r < 4; ++r) {
                float s1 = 0.f, s2 = 0.f;
#pragma unroll
                for (int j = 0; j < 4; ++j) { const float v = am[i][j][r]; s1 += v; s2 += v * v; }
#pragma unroll
                for (int m = 1; m < 16; m <<= 1) {
                    s1 += __shfl_xor(s1, m);
                    s2 += __shfl_xor(s2, m);
                }
                if (cc == 0) {
                    s_s1[cg2][rg2 * 32 + i * 16 + cr + r] = s1;
                    s_s2[cg2][rg2 * 32 + i * 16 + cr + r] = s2;
                }
            }
        __syncthreads();
        if (tid < 128) {
            const float a = s_s1[0][tid] + s_s1[1][tid];
            const float q = s_s2[0][tid] + s_s2[1][tid];
            const float mu = a * (1.f / 128.f);
            s_mu[tid] = mu;
            s_rs[tid] = rsqrtf(q * (1.f / 128.f) - mu * mu + LN_EPS);
        }
        __syncthreads();
        // LN1 apply: write x3 -> lX (k8-pack) + x3stash (HBM, same-block reuse)
        bf16_t* lX0 = &lW1[0][0];
#pragma unroll
        for (int j = 0; j < 4; ++j) {
            const int col = cg2 * 64 + j * 16 + cc;
            const float gg = n1g[col], bbta = n1b[col];
#pragma unroll
            for (int i = 0; i < 2; ++i)
#pragma unroll
                for (int r = 0; r < 4; ++r) {
                    const int rloc = rg2 * 32 + i * 16 + cr + r;
                    const bf16_t v = (bf16_t)((am[i][j][r] - s_mu[rloc]) * s_rs[rloc] * gg + bbta);
                    lX0[((col >> 3) * 128 + rloc) * 8 + (col & 7)] = v;
                    x3stash[(size_t)(row0 + rloc) * 128 + col] = v;
                }
        }
    }
    __syncthreads();

    // ---- lift x3 A-frags to VGPRs from lX ----
    bf16_t* lX = &lW1[0][0];
    bf16x8 afx[4][4];                   // [ir: 64 rows][kk: K=128]
#pragma unroll
    for (int ir = 0; ir < 4; ++ir)
#pragma unroll
        for (int kk = 0; kk < 4; ++kk)
            afx[ir][kk] = *(const bf16x8*)&lX[((kk * 4 + ko) * 128 + wr + ir * 16 + rl) * 8];
    asm volatile("s_waitcnt lgkmcnt(0)" ::: "memory");
    __builtin_amdgcn_s_barrier();       // afx reads drained block-wide before overwrite
    __builtin_amdgcn_sched_barrier(0);

    auto stage_chunk = [&](int chn, bf16_t* w1d, bf16_t* w2d) {
#pragma unroll
        for (int it = 0; it < 2; ++it) {
            const int c = it * 512 + tid, g = c >> 6, n = c & 63;
            GLD_LDS16(W1p + ((size_t)g * 2048 + chn * 64 + n) * 8, w1d + c * 8);
        }
#pragma unroll
        for (int it = 0; it < 2; ++it) {
            const int c = it * 512 + tid, g = c >> 7, n = c & 127;
            GLD_LDS16(W2p + ((size_t)(chn * 8 + g) * 128 + n) * 8, w2d + c * 8);
        }
    };

    f32x4 xacc[4][4] = {};              // 64 rows x 64 cols (K-half partial)

    // GEMM1 (swapped): yT = W1chunk^T @ x3^T ; wave: 64 rows x 16 dff
    auto gemm1 = [&](int chn, const bf16_t* w1c, bf16_t* ydst) {
        f32x4 yacc[4] = {};
        __builtin_amdgcn_s_setprio(1);
#pragma unroll
        for (int kk = 0; kk < 4; ++kk) {
            const bf16x8 bw = *(const bf16x8*)&w1c[((kk * 4 + ko) * 64 + wc1 + rl) * 8];
#pragma unroll
            for (int ir = 0; ir < 4; ++ir)
                yacc[ir] = __builtin_amdgcn_mfma_f32_16x16x32_bf16(bw, afx[ir][kk], yacc[ir], 0, 0, 0);
        }
        __builtin_amdgcn_s_setprio(0);
        // bias+relu -> lY in A-frag layout [dff>>3][row][8]
        const int dffb = wc1 + cr;
        const float4 bb = *(const float4*)(b1 + chn * 64 + dffb);
#pragma unroll
        for (int ir = 0; ir < 4; ++ir) {
            const int rowx = wr + ir * 16 + cc;
            union { bf16_t b[4]; uint2 u; } pk;
            pk.b[0] = (bf16_t)fmaxf(yacc[ir][0] + bb.x, 0.f);
            pk.b[1] = (bf16_t)fmaxf(yacc[ir][1] + bb.y, 0.f);
            pk.b[2] = (bf16_t)fmaxf(yacc[ir][2] + bb.z, 0.f);
            pk.b[3] = (bf16_t)fmaxf(yacc[ir][3] + bb.w, 0.f);
            *(uint2*)&ydst[((dffb >> 3) * 128 + rowx) * 8 + (dffb & 7)] = pk.u;
        }
    };

    // GEMM2: xacc += y[64 rows][K-half 32] @ W2chunk[K-half][64 cols]
    auto gemm2 = [&](const bf16_t* w2c, const bf16_t* ysrc) {
        bf16x8 ay[4], bw2[4];
#pragma unroll
        for (int ir = 0; ir < 4; ++ir)
            ay[ir] = *(const bf16x8*)&ysrc[((kh * 4 + ko) * 128 + wr + ir * 16 + rl) * 8];
#pragma unroll
        for (int j = 0; j < 4; ++j)
            bw2[j] = *(const bf16x8*)&w2c[((kh * 4 + ko) * 128 + wc2 + j * 16 + rl) * 8];
        __builtin_amdgcn_s_setprio(1);
#pragma unroll
        for (int ir = 0; ir < 4; ++ir)
#pragma unroll
            for (int j = 0; j < 4; ++j)
                xacc[ir][j] = __builtin_amdgcn_mfma_f32_16x16x32_bf16(ay[ir], bw2[j], xacc[ir][j], 0, 0, 0);
        __builtin_amdgcn_s_setprio(0);
    };

    // ---- prologue: stage W1[0],W2[0] then W1[1],W2[1] (per-wave FIFO order) ----
#pragma unroll
    for (int pc = 0; pc < 2; ++pc)
        stage_chunk(pc, lW1[pc], lW2[pc]);
    asm volatile("s_waitcnt vmcnt(4)" ::: "memory");   // chunk0 ready; chunk1 in flight
    __builtin_amdgcn_s_barrier();
    __builtin_amdgcn_sched_barrier(0);

    // ---- interval 0: GEMM1(0) only ----
    stage_chunk(2, lW1[2], lW2[2]);
    gemm1(0, lW1[0], lY[0]);
    __builtin_amdgcn_sched_barrier(0);
    asm volatile("s_waitcnt vmcnt(4) lgkmcnt(0)" ::: "memory");   // chunk1 ready
    __builtin_amdgcn_s_barrier();
    __builtin_amdgcn_sched_barrier(0);

    // ---- steady state: interval i = GEMM1(i) + GEMM2(i-1) ----
    int r1 = 1, sb1 = 0, r2 = 0, sb2 = 3, p = 1;
#pragma unroll 1
    for (int i = 1; i < 32; ++i) {
        if (i < 30)
            stage_chunk(i + 2, lW1[sb1], lW2[sb2]);
        gemm1(i, lW1[r1], lY[p]);
        gemm2(lW2[r2], lY[p ^ 1]);
        __builtin_amdgcn_sched_barrier(0);
        if (i < 30)
            asm volatile("s_waitcnt vmcnt(4) lgkmcnt(0)" ::: "memory");
        else if (i == 30)
            asm volatile("s_waitcnt vmcnt(2) lgkmcnt(0)" ::: "memory");  // W1[31] done (issued first)
        else
            asm volatile("s_waitcnt vmcnt(0) lgkmcnt(0)" ::: "memory");  // W2[31] done
        __builtin_amdgcn_s_barrier();
        __builtin_amdgcn_sched_barrier(0);
        r1 = (r1 == 2) ? 0 : r1 + 1;
        sb1 = (sb1 == 2) ? 0 : sb1 + 1;
        r2 = (r2 == 3) ? 0 : r2 + 1;
        sb2 = (sb2 == 3) ? 0 : sb2 + 1;
        p ^= 1;
    }
    // ---- interval 32: GEMM2(31) (both K-halves) ----
    gemm2(lW2[3], lY[1]);

    // ---- K-split merge: kh=1 partials -> kh=0 via padded LDS exchange (once) ----
    __syncthreads();                    // weights dead; reuse lW1/lW2 as f32 scratch
    {
        const int q = (wave >> 1) & 3;  // (rg,cg) pair id shared by kh partners
        float* scr = (q < 2) ? ((float*)&lW1[0][0] + q * 4352)
                             : ((float*)&lW2[0][0] + (q - 2) * 4352);  // 64 lanes x 68 floats
        if (kh) {
#pragma unroll
            for (int ir = 0; ir < 4; ++ir)
#pragma unroll
                for (int j = 0; j < 4; ++j)
                    *(f32x4*)(scr + lane * 68 + (ir * 4 + j) * 4) = xacc[ir][j];
        }
        __syncthreads();
        if (!kh) {
#pragma unroll
            for (int ir = 0; ir < 4; ++ir)
#pragma unroll
                for (int j = 0; j < 4; ++j)
                    xacc[ir][j] += *(const f32x4*)(scr + lane * 68 + (ir * 4 + j) * 4);
        }
    }

    // ---- epilogue (kh=0 waves): + b2 + x3 residual, LN2, store fp32 ----
    if (!kh) {
#pragma unroll
        for (int j = 0; j < 4; ++j) {
            const int col = wc2 + j * 16 + cc;
            const float bb = b2[col];
#pragma unroll
            for (int ir = 0; ir < 4; ++ir)
#pragma unroll
                for (int r = 0; r < 4; ++r) {
                    const int row = wr + ir * 16 + cr + r;
                    xacc[ir][j][r] += bb + (float)x3stash[(size_t)(row0 + row) * 128 + col];
                }
        }
#pragma unroll
        for (int ir = 0; ir < 4; ++ir)
#pragma unroll
            for (int r = 0; r < 4; ++r) {
                float s1v = 0.f, s2v = 0.f;
#pragma unroll
                for (int j = 0; j < 4; ++j) { const float v = xacc[ir][j][r]; s1v += v; s2v += v * v; }
#pragma unroll
                for (int m = 1; m < 16; m <<= 1) {
                    s1v += __shfl_xor(s1v, m);
                    s2v += __shfl_xor(s2v, m);
                }
                if (cc == 0) {
                    s_s1[cg][wr + ir * 16 + cr + r] = s1v;
                    s_s2[cg][wr + ir * 16 + cr + r] = s2v;
                }
            }
    }
    __syncthreads();
    if (tid < 128) {
        const float a = s_s1[0][tid] + s_s1[1][tid];
        const float q = s_s2[0][tid] + s_s2[1][tid];
        const float mu = a * (1.f / 128.f);
        s_mu[tid] = mu;
        s_rs[tid] = rsqrtf(q * (1.f / 128.f) - mu * mu + LN_EPS);
    }
    __syncthreads();
    if (!kh) {
#pragma unroll
        for (int j = 0; j < 4; ++j) {
            const int col = wc2 + j * 16 + cc;
            const float gg = gamma[col], bb = beta[col];
#pragma unroll
            for (int ir = 0; ir < 4; ++ir)
#pragma unroll
                for (int r = 0; r < 4; ++r) {
                    const int rloc = wr + ir * 16 + cr + r;
                    out[(size_t)(row0 + rloc) * 128 + col] =
                        (xacc[ir][j][r] - s_mu[rloc]) * s_rs[rloc] * gg + bb;
                }
        }
    }
}

// ============ edge build: w = exp(leaky(score)); ONE packed 16B CSR record ============
__global__ __launch_bounds__(256) void edge_build(const float* __restrict__ evals,
                                                  const int* __restrict__ src,
                                                  const int* __restrict__ dst,
                                                  const float* __restrict__ el,
                                                  const float* __restrict__ er,
                                                  const float* __restrict__ ce,
                                                  int* __restrict__ cursor,
                                                  uint4* __restrict__ csr) {
    const int e = blockIdx.x * 256 + threadIdx.x;
    const int s = src[e], d = dst[e];
    const float ev = evals[e];
    const float4 l = *(const float4*)(el + (size_t)s * 4);
    const float4 r = *(const float4*)(er + (size_t)d * 4);
    const float4 c = *(const float4*)ce;
    float4 w;
    {
        float v;
        v = l.x + r.x + ev * c.x; v = v >= 0.f ? v : SLOPE * v; w.x = __expf(v);
        v = l.y + r.y + ev * c.y; v = v >= 0.f ? v : SLOPE * v; w.y = __expf(v);
        v = l.z + r.z + ev * c.z; v = v >= 0.f ? v : SLOPE * v; w.z = __expf(v);
        v = l.w + r.w + ev * c.w; v = v >= 0.f ? v : SLOPE * v; w.w = __expf(v);
    }
    const int pos = atomicAdd(&cursor[d], 1);
    if (pos < CAP) {
        uint4 rec;
        rec.x = (unsigned)__half_as_ushort(__float2half(w.x)) |
                ((unsigned)__half_as_ushort(__float2half(w.y)) << 16);
        rec.y = (unsigned)__half_as_ushort(__float2half(w.z)) |
                ((unsigned)__half_as_ushort(__float2half(w.w)) << 16);
        rec.z = (unsigned)s;
        rec.w = 0u;
        csr[(size_t)d * CAP + pos] = rec;
    }
}

__device__ inline float w_of(const uint4& rec, int ht) {
    const unsigned pair = (ht < 2) ? rec.x : rec.y;
    const unsigned sh = (ht & 1) ? (pair >> 16) : (pair & 0xffffu);
    return __half2float(__ushort_as_half((unsigned short)sh));
}

// ============ aggregate (fp8 gather, packed rec, 8-deep MLP) ============
__global__ __launch_bounds__(128) void aggregate_kernel(const unsigned char* __restrict__ ft8,
                                                        const bf16_t* __restrict__ res,
                                                        const int* __restrict__ cursor,
                                                        const uint4* __restrict__ csr,
                                                        const float* __restrict__ gat_bias,
                                                        bf16_t* __restrict__ x1) {
    const int n = blockIdx.x, t = threadIdx.x;
    __shared__ uint4 s_rec[CAP];
    const int deg = min(cursor[n], CAP);
    const int ht = t >> 5;
    if (t < deg) s_rec[t] = csr[(size_t)n * CAP + t];
    __syncthreads();
    float4 acc = {0.f, 0.f, 0.f, 0.f};
    float z = 0.f;
    int j = 0;
    for (; j + 8 <= deg; j += 8) {       // 8 VMEM loads in flight
        unsigned u[8];
        float w[8];
#pragma unroll
        for (int q = 0; q < 8; ++q) {
            const uint4 rc = s_rec[j + q];
            w[q] = w_of(rc, ht);
            u[q] = *(const unsigned*)(ft8 + (size_t)rc.z * 512 + t * 4);
        }
#pragma unroll
        for (int q = 0; q < 8; ++q) {
            z += w[q];
            const f32x2 lo = e4m3x2_to_f32<false>(u[q]), hi = e4m3x2_to_f32<true>(u[q]);
            acc.x += w[q] * lo[0]; acc.y += w[q] * lo[1];
            acc.z += w[q] * hi[0]; acc.w += w[q] * hi[1];
        }
    }
    for (; j < deg; ++j) {
        const uint4 rc = s_rec[j];
        const float w = w_of(rc, ht);
        z += w;
        const unsigned u = *(const unsigned*)(ft8 + (size_t)rc.z * 512 + t * 4);
        const f32x2 lo = e4m3x2_to_f32<false>(u);
        const f32x2 hi = e4m3x2_to_f32<true>(u);
        acc.x += w * lo[0]; acc.y += w * lo[1];
        acc.z += w * hi[0]; acc.w += w * hi[1];
    }
    const float rz = deg > 0 ? 1.f / z : 0.f;
    const uint2 ur = *(const uint2*)(res + (size_t)n * FDIM + t * 4);
    const float4 gb = ((const float4*)gat_bias)[t];
    union { bf16_t b[4]; uint2 u; } pk;
    pk.b[0] = (bf16_t)fmaxf(acc.x * rz + __uint_as_float(ur.x << 16) + gb.x, 0.f);
    pk.b[1] = (bf16_t)fmaxf(acc.y * rz + __uint_as_float(ur.x & 0xFFFF0000u) + gb.y, 0.f);
    pk.b[2] = (bf16_t)fmaxf(acc.z * rz + __uint_as_float(ur.y << 16) + gb.z, 0.f);
    pk.b[3] = (bf16_t)fmaxf(acc.w * rz + __uint_as_float(ur.y & 0xFFFF0000u) + gb.w, 0.f);
    *(uint2*)(x1 + (size_t)n * FDIM + t * 4) = pk.u;
}

extern "C" void kernel_launch(void* const* d_in, const int* in_sizes, int n_in,
                              void* d_out, int out_size, void* d_ws, size_t ws_size,
                              hipStream_t stream) {
    const float* h        = (const float*)d_in[0];
    const float* evals    = (const float*)d_in[1];
    const int*   src      = (const int*)d_in[2];
    const int*   dst      = (const int*)d_in[3];
    const float* W_fc     = (const float*)d_in[5];
    const float* attn_l   = (const float*)d_in[6];
    const float* attn_r   = (const float*)d_in[7];
    const float* W_fe     = (const float*)d_in[8];
    const float* attn_e   = (const float*)d_in[9];
    const float* W_res    = (const float*)d_in[10];
    const float* gat_bias = (const float*)d_in[11];
    const float* W_mha    = (const float*)d_in[12];
    const float* b_mha    = (const float*)d_in[13];
    const float* n1_g     = (const float*)d_in[14];
    const float* n1_b     = (const float*)d_in[15];
    const float* n2_g     = (const float*)d_in[16];
    const float* n2_b     = (const float*)d_in[17];
    const float* W1       = (const float*)d_in[18];
    const float* b1       = (const float*)d_in[19];
    const float* W2       = (const float*)d_in[20];
    const float* b2       = (const float*)d_in[21];

    char* ws = (char*)d_ws;
    unsigned char* ft8 = (unsigned char*)(ws + 0);   // 16MB  N x 512 fp8
    bf16_t* res     = (bf16_t*)(ws + 16777216ull);   // 32MB  N x 512
    bf16_t* x1      = (bf16_t*)(ws + 50331648ull);   // 32MB  N x 512
    uint4*  csr     = (uint4*) (ws + 83886080ull);   // 32MB  N x CAP x 16B packed
    bf16_t* x3b     = (bf16_t*)(ws + 125829120ull);  // 8MB   N x 128
    bf16_t* hb      = (bf16_t*)(ws + 134217728ull);  // 8MB   N x 128
    bf16_t* Wfc_p   = (bf16_t*)(ws + 142606336ull);  // 128KB
    bf16_t* Wres_p  = (bf16_t*)(ws + 142737408ull);  // 128KB
    bf16_t* Wmha_p  = (bf16_t*)(ws + 142868480ull);  // 128KB
    bf16_t* W1_p    = (bf16_t*)(ws + 142999552ull);  // 512KB
    bf16_t* W2_p    = (bf16_t*)(ws + 143523840ull);  // 512KB
    float*  el      = (float*) (ws + 144048128ull);  // 512KB
    float*  er      = (float*) (ws + 144572416ull);  // 512KB
    float*  ce      = (float*) (ws + 145096704ull);  // 16B
    int*    cursor  = (int*)   (ws + 145096768ull);  // 128KB

    if (ws_size < 146000000ull) return;

    (void)hipMemsetAsync(cursor, 0, 131072, stream);

    prep_kernel<<<4449, 256, 0, stream>>>(h, hb, W_fc, Wfc_p, W_res, Wres_p,
                                          W_mha, Wmha_p, W1, W1_p, W2, W2_p,
                                          W_fe, attn_e, ce);
    gemm_ftres<<<dim3(4, 256), 256, 0, stream>>>(hb, Wfc_p, Wres_p, attn_l, attn_r, ft8, el, er, res);
    edge_build<<<E_EDGES / 256, 256, 0, stream>>>(evals, src, dst, el, er, ce, cursor, csr);
    aggregate_kernel<<<N_NODES, 128, 0, stream>>>(ft8, res, cursor, csr, gat_bias, x1);
    ffn_mega<<<256, 512, 0, stream>>>(x1, Wmha_p, b_mha, h, n1_g, n1_b, x3b,
                                      W1_p, b1, W2_p, b2, n2_g, n2_b, (float*)d_out);
}

// Round 9
// 270.921 us; speedup vs baseline: 1.0454x; 1.0454x over previous
//
#include <hip/hip_runtime.h>
#include <hip/hip_bf16.h>
#include <hip/hip_fp16.h>

#define N_NODES 32768
#define E_EDGES 524288
#define HIDDIM 128
#define FDIM 512
#define DFF 2048
#define LN_EPS 1e-5f
#define SLOPE 0.2f
#define CAP 64          // CSR slot capacity per dst (Poisson(16): P(>64) ~ 1e-19)

typedef __bf16 bf16_t;
typedef __bf16 bf16x8 __attribute__((ext_vector_type(8)));
typedef float f32x4 __attribute__((ext_vector_type(4)));
typedef float f32x2 __attribute__((ext_vector_type(2)));

#define GLD_LDS16(gp, lp) __builtin_amdgcn_global_load_lds( \
    (const __attribute__((address_space(1))) unsigned int*)(gp), \
    (__attribute__((address_space(3))) unsigned int*)(lp), 16, 0, 0)

// ---------- fp8 e4m3 codec (HW cvt when available) ----------
__device__ inline unsigned char f32_to_e4m3(float v) {
#if __has_builtin(__builtin_amdgcn_cvt_pk_fp8_f32)
    return (unsigned char)(__builtin_amdgcn_cvt_pk_fp8_f32(v, v, 0, false) & 0xff);
#else
    unsigned bits = __float_as_uint(v);
    unsigned sign = (bits >> 24) & 0x80;
    float av = fabsf(v);
    if (av >= 448.f) return (unsigned char)(sign | 0x7E);
    int e = (int)((bits >> 23) & 0xFF) - 127;
    if (e < -6) { int n = (int)rintf(av * 512.f); return (unsigned char)(sign | n); }
    float ulp = exp2f((float)(e - 3));
    int n = (int)rintf(av / ulp);
    if (n == 16) { e += 1; n = 8; }
    return (unsigned char)(sign | ((e + 7) << 3) | (n - 8));
#endif
}
template<bool HI>
__device__ inline f32x2 e4m3x2_to_f32(unsigned u) {
#if __has_builtin(__builtin_amdgcn_cvt_pk_f32_fp8)
    return __builtin_amdgcn_cvt_pk_f32_fp8(u, HI);
#else
    f32x2 r;
    unsigned b0 = HI ? ((u >> 16) & 0xff) : (u & 0xff);
    unsigned b1 = HI ? ((u >> 24) & 0xff) : ((u >> 8) & 0xff);
    unsigned bs[2] = {b0, b1};
    for (int i = 0; i < 2; ++i) {
        unsigned b = bs[i];
        float s = (b & 0x80) ? -1.f : 1.f;
        int e = (b >> 3) & 15, m = b & 7;
        float v = e ? (8 + m) * exp2f((float)(e - 10)) : m * exp2f(-9.f);
        r[i] = s * v;
    }
    return r;
#endif
}

// ============ prep: h->bf16, all weight k8-packs, ce — one dispatch ============
__device__ inline void pack_range(const float* __restrict__ B, bf16_t* __restrict__ out,
                                  int id, int N) {
    const int g = id / N, n = id % N;
    union { bf16_t b[8]; uint4 u; } pk;
#pragma unroll
    for (int j = 0; j < 8; ++j) pk.b[j] = (bf16_t)B[(size_t)(g * 8 + j) * N + n];
    *(uint4*)(out + (size_t)id * 8) = pk.u;
}

__global__ __launch_bounds__(256) void prep_kernel(const float* __restrict__ h, bf16_t* __restrict__ hb,
                                                   const float* __restrict__ W_fc, bf16_t* __restrict__ Wfc_p,
                                                   const float* __restrict__ W_res, bf16_t* __restrict__ Wres_p,
                                                   const float* __restrict__ W_mha, bf16_t* __restrict__ Wmha_p,
                                                   const float* __restrict__ W1, bf16_t* __restrict__ W1_p,
                                                   const float* __restrict__ W2, bf16_t* __restrict__ W2_p,
                                                   const float* __restrict__ W_fe, const float* __restrict__ attn_e,
                                                   float* __restrict__ ce) {
    int bid = blockIdx.x;
    const int tid = threadIdx.x;
    if (bid < 4096) {                       // h fp32 -> bf16 (4 elems/thread)
        const int id = bid * 256 + tid;
        const float4 v = ((const float4*)h)[id];
        union { bf16_t b[4]; uint2 u; } pk;
        pk.b[0] = (bf16_t)v.x; pk.b[1] = (bf16_t)v.y; pk.b[2] = (bf16_t)v.z; pk.b[3] = (bf16_t)v.w;
        *(uint2*)(hb + (size_t)id * 4) = pk.u;
        return;
    }
    bid -= 4096;
    if (bid < 32)  { pack_range(W_fc,  Wfc_p,  bid * 256 + tid, 512);  return; }
    bid -= 32;
    if (bid < 32)  { pack_range(W_res, Wres_p, bid * 256 + tid, 512);  return; }
    bid -= 32;
    if (bid < 32)  { pack_range(W_mha, Wmha_p, bid * 256 + tid, 128);  return; }
    bid -= 32;
    if (bid < 128) { pack_range(W1,    W1_p,   bid * 256 + tid, 2048); return; }
    bid -= 128;
    if (bid < 128) { pack_range(W2,    W2_p,   bid * 256 + tid, 128);  return; }
    // ce
    if (tid < 128) {
        const float4 w = ((const float4*)W_fe)[tid];
        const float4 a = ((const float4*)attn_e)[tid];
        float p = w.x * a.x + w.y * a.y + w.z * a.z + w.w * a.w;
        for (int off = 16; off; off >>= 1) p += __shfl_down(p, off, 32);
        if ((tid & 31) == 0) ce[tid >> 5] = p;
    }
}

// ============ fused ft+res GEMM: shared A panel (hb), two B matrices ============
__global__ __launch_bounds__(256, 2) void gemm_ftres(const bf16_t* __restrict__ A,
                                                     const bf16_t* __restrict__ Bf,
                                                     const bf16_t* __restrict__ Brs,
                                                     const float* __restrict__ attn_l,
                                                     const float* __restrict__ attn_r,
                                                     unsigned char* __restrict__ ft8,
                                                     float* __restrict__ el,
                                                     float* __restrict__ er,
                                                     bf16_t* __restrict__ res) {
    __shared__ __align__(16) bf16_t lA[4096];
    __shared__ __align__(16) bf16_t lBf[4096];
    __shared__ __align__(16) bf16_t lBr[4096];
    __shared__ float s_el[2][128], s_er[2][128];
    const int tid = threadIdx.x, lane = tid & 63, wave = tid >> 6;
    const int wm = (wave >> 1) * 64, wn = (wave & 1) * 64;
    const int row0 = blockIdx.y * 128;
    const int head = blockIdx.x, col0 = head * 128;
    const int ko = lane >> 4, rl = lane & 15;
    f32x4 accf[4][4] = {};
    f32x4 accr[4][4] = {};
    const int c0 = tid, c1 = tid + 256;
    const int g0 = c0 >> 7, m0 = c0 & 127;
    const int g1 = c1 >> 7, m1 = c1 & 127;
    for (int k0 = 0; k0 < 128; k0 += 32) {
        __syncthreads();
        GLD_LDS16(A + (size_t)(row0 + m0) * 128 + k0 + g0 * 8, lA + c0 * 8);
        GLD_LDS16(A + (size_t)(row0 + m1) * 128 + k0 + g1 * 8, lA + c1 * 8);
        GLD_LDS16(Bf + ((size_t)(k0 / 8 + g0) * 512 + col0 + m0) * 8, lBf + c0 * 8);
        GLD_LDS16(Bf + ((size_t)(k0 / 8 + g1) * 512 + col0 + m1) * 8, lBf + c1 * 8);
        GLD_LDS16(Brs + ((size_t)(k0 / 8 + g0) * 512 + col0 + m0) * 8, lBr + c0 * 8);
        GLD_LDS16(Brs + ((size_t)(k0 / 8 + g1) * 512 + col0 + m1) * 8, lBr + c1 * 8);
        __syncthreads();
        bf16x8 af[4], bff[4], bfr[4];
#pragma unroll
        for (int i = 0; i < 4; ++i) {
            af[i]  = *(const bf16x8*)&lA[(ko * 128 + wm + i * 16 + rl) * 8];
            bff[i] = *(const bf16x8*)&lBf[(ko * 128 + wn + i * 16 + rl) * 8];
            bfr[i] = *(const bf16x8*)&lBr[(ko * 128 + wn + i * 16 + rl) * 8];
        }
#pragma unroll
        for (int i = 0; i < 4; ++i)
#pragma unroll
            for (int j = 0; j < 4; ++j) {
                accf[i][j] = __builtin_amdgcn_mfma_f32_16x16x32_bf16(af[i], bff[j], accf[i][j], 0, 0, 0);
                accr[i][j] = __builtin_amdgcn_mfma_f32_16x16x32_bf16(af[i], bfr[j], accr[i][j], 0, 0, 0);
            }
    }
    const int cr = (lane >> 4) * 4, cc = lane & 15;
    float al[4], ar[4];
#pragma unroll
    for (int j = 0; j < 4; ++j) {
        al[j] = attn_l[col0 + wn + j * 16 + cc];
        ar[j] = attn_r[col0 + wn + j * 16 + cc];
    }
#pragma unroll
    for (int i = 0; i < 4; ++i)
#pragma unroll
        for (int r = 0; r < 4; ++r) {
            const int row = row0 + wm + i * 16 + cr + r;
            float pel = 0.f, per = 0.f;
#pragma unroll
            for (int j = 0; j < 4; ++j) {
                const int col = col0 + wn + j * 16 + cc;
                const float v = accf[i][j][r];
                ft8[(size_t)row * 512 + col] = f32_to_e4m3(v);
                res[(size_t)row * 512 + col] = (bf16_t)accr[i][j][r];
                pel += v * al[j];
                per += v * ar[j];
            }
#pragma unroll
            for (int m = 1; m < 16; m <<= 1) {
                pel += __shfl_xor(pel, m);
                per += __shfl_xor(per, m);
            }
            if (cc == 0) {
                s_el[wn >> 6][wm + i * 16 + cr + r] = pel;
                s_er[wn >> 6][wm + i * 16 + cr + r] = per;
            }
        }
    __syncthreads();
    if (tid < 128) {
        el[(size_t)(row0 + tid) * 4 + head] = s_el[0][tid] + s_el[1][tid];
        er[(size_t)(row0 + tid) * 4 + head] = s_er[0][tid] + s_er[1][tid];
    }
}

// ============ ffn_mega v2: mha GEMM + LN1 + FFN + LN2 in one kernel ============
// Phase 0 now PIPELINED: 4 staging buffers carved from the (dead during phase-0)
// lW2[0..3] (16KB each: x1-panel 8KB + Wm-chunk 8KB), prefetch depth 3, ONE
// barrier/step, counted s_waitcnt vmcnt(4) (never 0 until tail) — T3/T4 applied.
// x3stash (8MB HBM write + 8MB read) ELIMINATED: the LN2 residual (64 bf16/thread,
// kh=0 waves) is extracted from lX into 32 packed VGPRs at the afx lift, before
// the main loop overwrites lX. Main loop = v7 K-split schedule, unchanged.
__global__ __launch_bounds__(512, 2) void ffn_mega(const bf16_t* __restrict__ x1,
                                                   const bf16_t* __restrict__ Wm,
                                                   const float* __restrict__ b_mha,
                                                   const float* __restrict__ h0,
                                                   const float* __restrict__ n1g,
                                                   const float* __restrict__ n1b,
                                                   const bf16_t* __restrict__ W1p,
                                                   const float* __restrict__ b1,
                                                   const bf16_t* __restrict__ W2p,
                                                   const float* __restrict__ b2,
                                                   const float* __restrict__ gamma,
                                                   const float* __restrict__ beta,
                                                   float* __restrict__ out) {
    __shared__ __align__(16) bf16_t lW1[3][8192];   // [buf][g16][64][8]; [0..1] doubles as x3 (lX)
    __shared__ __align__(16) bf16_t lW2[4][8192];   // [buf][g8][128][8]; phase-0: 4 staging bufs
    __shared__ __align__(16) bf16_t lY[2][8192];    // [par][dff>>3][128][8]
    __shared__ float s_s1[2][128], s_s2[2][128], s_mu[128], s_rs[128];
    const int tid = threadIdx.x, lane = tid & 63, wave = tid >> 6;
    const int kh  = wave & 1;          // GEMM2 K-half
    const int ds  = wave & 3;          // GEMM1 dff slice (16 wide)
    const int cg  = (wave >> 1) & 1;   // GEMM2 col group (64 wide)
    const int rg  = wave >> 2;         // row group (64 rows)
    const int wr  = rg * 64;
    const int wc1 = ds * 16;
    const int wc2 = cg * 64;
    const int row0 = blockIdx.x * 128;
    const int ko = lane >> 4, rl = lane & 15;
    const int cr = ko * 4, cc = rl;

    // ---- phase 0 (pipelined): mha GEMM 128x128 K=512 + LN1 -> x3 in lX ----
    {
        const int rg2 = wave >> 1;      // 4 row-groups x 32 rows
        const int cg2 = wave & 1;       // 2 col-groups x 64 cols
        const int gg = tid >> 7, mm = tid & 127;
        auto stage0 = [&](int s) {
            bf16_t* lab = &lW2[s & 3][0];     // [0..4095]=x1 panel, [4096..8191]=Wm chunk
            GLD_LDS16(x1 + (size_t)(row0 + mm) * 512 + s * 32 + gg * 8, lab + tid * 8);
            GLD_LDS16(Wm + ((size_t)(s * 4 + gg) * 128 + mm) * 8, lab + 4096 + tid * 8);
        };
        f32x4 am[2][4] = {};
        stage0(0); stage0(1); stage0(2);     // 6 GLD/thread in flight
        for (int s = 0; s < 16; ++s) {
            __builtin_amdgcn_sched_barrier(0);
            if (s < 14)       asm volatile("s_waitcnt vmcnt(4)" ::: "memory");  // step s landed
            else if (s == 14) asm volatile("s_waitcnt vmcnt(2)" ::: "memory");
            else              asm volatile("s_waitcnt vmcnt(0)" ::: "memory");
            __builtin_amdgcn_s_barrier();     // all waves' step-s staging visible
            __builtin_amdgcn_sched_barrier(0);
            if (s + 3 < 16) stage0(s + 3);    // overwrites buf[(s-1)&3]: reads done pre-barrier
            const bf16_t* lab = &lW2[s & 3][0];
            bf16x8 af[2], bfm[4];
#pragma unroll
            for (int i = 0; i < 2; ++i)
                af[i] = *(const bf16x8*)&lab[(ko * 128 + rg2 * 32 + i * 16 + rl) * 8];
#pragma unroll
            for (int j = 0; j < 4; ++j)
                bfm[j] = *(const bf16x8*)&lab[4096 + (ko * 128 + cg2 * 64 + j * 16 + rl) * 8];
            __builtin_amdgcn_s_setprio(1);
#pragma unroll
            for (int i = 0; i < 2; ++i)
#pragma unroll
                for (int j = 0; j < 4; ++j)
                    am[i][j] = __builtin_amdgcn_mfma_f32_16x16x32_bf16(af[i], bfm[j], am[i][j], 0, 0, 0);
            __builtin_amdgcn_s_setprio(0);
        }
        // bias + relu + h0 residual
#pragma unroll
        for (int j = 0; j < 4; ++j) {
            const int col = cg2 * 64 + j * 16 + cc;
            const float bb = b_mha[col];
#pragma unroll
            for (int i = 0; i < 2; ++i)
#pragma unroll
                for (int r = 0; r < 4; ++r) {
                    const int row = row0 + rg2 * 32 + i * 16 + cr + r;
                    am[i][j][r] = fmaxf(am[i][j][r] + bb, 0.f) + h0[(size_t)row * 128 + col];
                }
        }
        // LN1 stats
#pragma unroll
        for (int i = 0; i < 2; ++i)
#pragma unroll
            for (int r = 0; r < 4; ++r) {
                float s1 = 0.f, s2 = 0.f;
#pragma unroll
                for (int j = 0; j < 4; ++j) { const float v = am[i][j][r]; s1 += v; s2 += v * v; }
#pragma unroll
                for (int m = 1; m < 16; m <<= 1) {
                    s1 += __shfl_xor(s1, m);
                    s2 += __shfl_xor(s2, m);
                }
                if (cc == 0) {
                    s_s1[cg2][rg2 * 32 + i * 16 + cr + r] = s1;
                    s_s2[cg2][rg2 * 32 + i * 16 + cr + r] = s2;
                }
            }
        __syncthreads();
        if (tid < 128) {
            const float a = s_s1[0][tid] + s_s1[1][tid];
            const float q = s_s2[0][tid] + s_s2[1][tid];
            const float mu = a * (1.f / 128.f);
            s_mu[tid] = mu;
            s_rs[tid] = rsqrtf(q * (1.f / 128.f) - mu * mu + LN_EPS);
        }
        __syncthreads();
        // LN1 apply: write x3 -> lX (k8-pack) only (no HBM stash)
        bf16_t* lX0 = &lW1[0][0];
#pragma unroll
        for (int j = 0; j < 4; ++j) {
            const int col = cg2 * 64 + j * 16 + cc;
            const float gg2 = n1g[col], bbta = n1b[col];
#pragma unroll
            for (int i = 0; i < 2; ++i)
#pragma unroll
                for (int r = 0; r < 4; ++r) {
                    const int rloc = rg2 * 32 + i * 16 + cr + r;
                    lX0[((col >> 3) * 128 + rloc) * 8 + (col & 7)] =
                        (bf16_t)((am[i][j][r] - s_mu[rloc]) * s_rs[rloc] * gg2 + bbta);
                }
        }
    }
    __syncthreads();

    // ---- lift x3 A-frags to VGPRs + extract LN2-residual values (kh=0) ----
    bf16_t* lX = &lW1[0][0];
    bf16x8 afx[4][4];                   // [ir: 64 rows][kk: K=128]
#pragma unroll
    for (int ir = 0; ir < 4; ++ir)
#pragma unroll
        for (int kk = 0; kk < 4; ++kk)
            afx[ir][kk] = *(const bf16x8*)&lX[((kk * 4 + ko) * 128 + wr + ir * 16 + rl) * 8];
    unsigned x3p[32];                   // 64 bf16 packed 2/dword; used only by kh=0
    if (!kh) {
#pragma unroll
        for (int ir = 0; ir < 4; ++ir)
#pragma unroll
            for (int j = 0; j < 4; ++j)
#pragma unroll
                for (int rr = 0; rr < 2; ++rr) {
                    const int col = wc2 + j * 16 + cc;
                    const int rw = wr + ir * 16 + cr + rr * 2;
                    const unsigned short a = *(const unsigned short*)&lX[((col >> 3) * 128 + rw) * 8 + (col & 7)];
                    const unsigned short b = *(const unsigned short*)&lX[((col >> 3) * 128 + rw + 1) * 8 + (col & 7)];
                    x3p[ir * 8 + j * 2 + rr] = (unsigned)a | ((unsigned)b << 16);
                }
    }
    asm volatile("s_waitcnt lgkmcnt(0)" ::: "memory");
    __builtin_amdgcn_s_barrier();       // lX reads drained block-wide before overwrite
    __builtin_amdgcn_sched_barrier(0);

    auto stage_chunk = [&](int chn, bf16_t* w1d, bf16_t* w2d) {
#pragma unroll
        for (int it = 0; it < 2; ++it) {
            const int c = it * 512 + tid, g = c >> 6, n = c & 63;
            GLD_LDS16(W1p + ((size_t)g * 2048 + chn * 64 + n) * 8, w1d + c * 8);
        }
#pragma unroll
        for (int it = 0; it < 2; ++it) {
            const int c = it * 512 + tid, g = c >> 7, n = c & 127;
            GLD_LDS16(W2p + ((size_t)(chn * 8 + g) * 128 + n) * 8, w2d + c * 8);
        }
    };

    f32x4 xacc[4][4] = {};              // 64 rows x 64 cols (K-half partial)

    // GEMM1 (swapped): yT = W1chunk^T @ x3^T ; wave: 64 rows x 16 dff
    auto gemm1 = [&](int chn, const bf16_t* w1c, bf16_t* ydst) {
        f32x4 yacc[4] = {};
        __builtin_amdgcn_s_setprio(1);
#pragma unroll
        for (int kk = 0; kk < 4; ++kk) {
            const bf16x8 bw = *(const bf16x8*)&w1c[((kk * 4 + ko) * 64 + wc1 + rl) * 8];
#pragma unroll
            for (int ir = 0; ir < 4; ++ir)
                yacc[ir] = __builtin_amdgcn_mfma_f32_16x16x32_bf16(bw, afx[ir][kk], yacc[ir], 0, 0, 0);
        }
        __builtin_amdgcn_s_setprio(0);
        // bias+relu -> lY in A-frag layout [dff>>3][row][8]
        const int dffb = wc1 + cr;
        const float4 bb = *(const float4*)(b1 + chn * 64 + dffb);
#pragma unroll
        for (int ir = 0; ir < 4; ++ir) {
            const int rowx = wr + ir * 16 + cc;
            union { bf16_t b[4]; uint2 u; } pk;
            pk.b[0] = (bf16_t)fmaxf(yacc[ir][0] + bb.x, 0.f);
            pk.b[1] = (bf16_t)fmaxf(yacc[ir][1] + bb.y, 0.f);
            pk.b[2] = (bf16_t)fmaxf(yacc[ir][2] + bb.z, 0.f);
            pk.b[3] = (bf16_t)fmaxf(yacc[ir][3] + bb.w, 0.f);
            *(uint2*)&ydst[((dffb >> 3) * 128 + rowx) * 8 + (dffb & 7)] = pk.u;
        }
    };

    // GEMM2: xacc += y[64 rows][K-half 32] @ W2chunk[K-half][64 cols]
    auto gemm2 = [&](const bf16_t* w2c, const bf16_t* ysrc) {
        bf16x8 ay[4], bw2[4];
#pragma unroll
        for (int ir = 0; ir < 4; ++ir)
            ay[ir] = *(const bf16x8*)&ysrc[((kh * 4 + ko) * 128 + wr + ir * 16 + rl) * 8];
#pragma unroll
        for (int j = 0; j < 4; ++j)
            bw2[j] = *(const bf16x8*)&w2c[((kh * 4 + ko) * 128 + wc2 + j * 16 + rl) * 8];
        __builtin_amdgcn_s_setprio(1);
#pragma unroll
        for (int ir = 0; ir < 4; ++ir)
#pragma unroll
            for (int j = 0; j < 4; ++j)
                xacc[ir][j] = __builtin_amdgcn_mfma_f32_16x16x32_bf16(ay[ir], bw2[j], xacc[ir][j], 0, 0, 0);
        __builtin_amdgcn_s_setprio(0);
    };

    // ---- prologue: stage W1[0],W2[0] then W1[1],W2[1] (per-wave FIFO order) ----
#pragma unroll
    for (int pc = 0; pc < 2; ++pc)
        stage_chunk(pc, lW1[pc], lW2[pc]);
    asm volatile("s_waitcnt vmcnt(4)" ::: "memory");   // chunk0 ready; chunk1 in flight
    __builtin_amdgcn_s_barrier();
    __builtin_amdgcn_sched_barrier(0);

    // ---- interval 0: GEMM1(0) only ----
    stage_chunk(2, lW1[2], lW2[2]);
    gemm1(0, lW1[0], lY[0]);
    __builtin_amdgcn_sched_barrier(0);
    asm volatile("s_waitcnt vmcnt(4) lgkmcnt(0)" ::: "memory");   // chunk1 ready
    __builtin_amdgcn_s_barrier();
    __builtin_amdgcn_sched_barrier(0);

    // ---- steady state: interval i = GEMM1(i) + GEMM2(i-1) ----
    int r1 = 1, sb1 = 0, r2 = 0, sb2 = 3, p = 1;
#pragma unroll 1
    for (int i = 1; i < 32; ++i) {
        if (i < 30)
            stage_chunk(i + 2, lW1[sb1], lW2[sb2]);
        gemm1(i, lW1[r1], lY[p]);
        gemm2(lW2[r2], lY[p ^ 1]);
        __builtin_amdgcn_sched_barrier(0);
        if (i < 30)
            asm volatile("s_waitcnt vmcnt(4) lgkmcnt(0)" ::: "memory");
        else if (i == 30)
            asm volatile("s_waitcnt vmcnt(2) lgkmcnt(0)" ::: "memory");  // W1[31] done (issued first)
        else
            asm volatile("s_waitcnt vmcnt(0) lgkmcnt(0)" ::: "memory");  // W2[31] done
        __builtin_amdgcn_s_barrier();
        __builtin_amdgcn_sched_barrier(0);
        r1 = (r1 == 2) ? 0 : r1 + 1;
        sb1 = (sb1 == 2) ? 0 : sb1 + 1;
        r2 = (r2 == 3) ? 0 : r2 + 1;
        sb2 = (sb2 == 3) ? 0 : sb2 + 1;
        p ^= 1;
    }
    // ---- interval 32: GEMM2(31) (both K-halves) ----
    gemm2(lW2[3], lY[1]);

    // ---- K-split merge: kh=1 partials -> kh=0 via padded LDS exchange (once) ----
    __syncthreads();                    // weights dead; reuse lW1/lW2 as f32 scratch
    {
        const int q = (wave >> 1) & 3;  // (rg,cg) pair id shared by kh partners
        float* scr = (q < 2) ? ((float*)&lW1[0][0] + q * 4352)
                             : ((float*)&lW2[0][0] + (q - 2) * 4352);  // 64 lanes x 68 floats
        if (kh) {
#pragma unroll
            for (int ir = 0; ir < 4; ++ir)
#pragma unroll
                for (int j = 0; j < 4; ++j)
                    *(f32x4*)(scr + lane * 68 + (ir * 4 + j) * 4) = xacc[ir][j];
        }
        __syncthreads();
        if (!kh) {
#pragma unroll
            for (int ir = 0; ir < 4; ++ir)
#pragma unroll
                for (int j = 0; j < 4; ++j)
                    xacc[ir][j] += *(const f32x4*)(scr + lane * 68 + (ir * 4 + j) * 4);
        }
    }

    // ---- epilogue (kh=0 waves): + b2 + x3 residual (VGPR), LN2, store fp32 ----
    if (!kh) {
#pragma unroll
        for (int j = 0; j < 4; ++j) {
            const int col = wc2 + j * 16 + cc;
            const float bb = b2[col];
#pragma unroll
            for (int ir = 0; ir < 4; ++ir)
#pragma unroll
                for (int r = 0; r < 4; ++r) {
                    const unsigned dw = x3p[ir * 8 + j * 2 + (r >> 1)];
                    const float xv = __uint_as_float((r & 1) ? (dw & 0xFFFF0000u) : (dw << 16));
                    xacc[ir][j][r] += bb + xv;
                }
        }
#pragma unroll
        for (int ir = 0; ir < 4; ++ir)
#pragma unroll
            for (int r = 0; r < 4; ++r) {
                float s1v = 0.f, s2v = 0.f;
#pragma unroll
                for (int j = 0; j < 4; ++j) { const float v = xacc[ir][j][r]; s1v += v; s2v += v * v; }
#pragma unroll
                for (int m = 1; m < 16; m <<= 1) {
                    s1v += __shfl_xor(s1v, m);
                    s2v += __shfl_xor(s2v, m);
                }
                if (cc == 0) {
                    s_s1[cg][wr + ir * 16 + cr + r] = s1v;
                    s_s2[cg][wr + ir * 16 + cr + r] = s2v;
                }
            }
    }
    __syncthreads();
    if (tid < 128) {
        const float a = s_s1[0][tid] + s_s1[1][tid];
        const float q = s_s2[0][tid] + s_s2[1][tid];
        const float mu = a * (1.f / 128.f);
        s_mu[tid] = mu;
        s_rs[tid] = rsqrtf(q * (1.f / 128.f) - mu * mu + LN_EPS);
    }
    __syncthreads();
    if (!kh) {
#pragma unroll
        for (int j = 0; j < 4; ++j) {
            const int col = wc2 + j * 16 + cc;
            const float gg = gamma[col], bb = beta[col];
#pragma unroll
            for (int ir = 0; ir < 4; ++ir)
#pragma unroll
                for (int r = 0; r < 4; ++r) {
                    const int rloc = wr + ir * 16 + cr + r;
                    out[(size_t)(row0 + rloc) * 128 + col] =
                        (xacc[ir][j][r] - s_mu[rloc]) * s_rs[rloc] * gg + bb;
                }
        }
    }
}

// ============ edge build: w = exp(leaky(score)); ONE packed 16B CSR record ============
__global__ __launch_bounds__(256) void edge_build(const float* __restrict__ evals,
                                                  const int* __restrict__ src,
                                                  const int* __restrict__ dst,
                                                  const float* __restrict__ el,
                                                  const float* __restrict__ er,
                                                  const float* __restrict__ ce,
                                                  int* __restrict__ cursor,
                                                  uint4* __restrict__ csr) {
    const int e = blockIdx.x * 256 + threadIdx.x;
    const int s = src[e], d = dst[e];
    const float ev = evals[e];
    const float4 l = *(const float4*)(el + (size_t)s * 4);
    const float4 r = *(const float4*)(er + (size_t)d * 4);
    const float4 c = *(const float4*)ce;
    float4 w;
    {
        float v;
        v = l.x + r.x + ev * c.x; v = v >= 0.f ? v : SLOPE * v; w.x = __expf(v);
        v = l.y + r.y + ev * c.y; v = v >= 0.f ? v : SLOPE * v; w.y = __expf(v);
        v = l.z + r.z + ev * c.z; v = v >= 0.f ? v : SLOPE * v; w.z = __expf(v);
        v = l.w + r.w + ev * c.w; v = v >= 0.f ? v : SLOPE * v; w.w = __expf(v);
    }
    const int pos = atomicAdd(&cursor[d], 1);
    if (pos < CAP) {
        uint4 rec;
        rec.x = (unsigned)__half_as_ushort(__float2half(w.x)) |
                ((unsigned)__half_as_ushort(__float2half(w.y)) << 16);
        rec.y = (unsigned)__half_as_ushort(__float2half(w.z)) |
                ((unsigned)__half_as_ushort(__float2half(w.w)) << 16);
        rec.z = (unsigned)s;
        rec.w = 0u;
        csr[(size_t)d * CAP + pos] = rec;
    }
}

__device__ inline float w_of(const uint4& rec, int ht) {
    const unsigned pair = (ht < 2) ? rec.x : rec.y;
    const unsigned sh = (ht & 1) ? (pair >> 16) : (pair & 0xffffu);
    return __half2float(__ushort_as_half((unsigned short)sh));
}

// ============ aggregate (fp8 gather, packed rec, 8-deep MLP) ============
__global__ __launch_bounds__(128) void aggregate_kernel(const unsigned char* __restrict__ ft8,
                                                        const bf16_t* __restrict__ res,
                                                        const int* __restrict__ cursor,
                                                        const uint4* __restrict__ csr,
                                                        const float* __restrict__ gat_bias,
                                                        bf16_t* __restrict__ x1) {
    const int n = blockIdx.x, t = threadIdx.x;
    __shared__ uint4 s_rec[CAP];
    const int deg = min(cursor[n], CAP);
    const int ht = t >> 5;
    if (t < deg) s_rec[t] = csr[(size_t)n * CAP + t];
    __syncthreads();
    float4 acc = {0.f, 0.f, 0.f, 0.f};
    float z = 0.f;
    int j = 0;
    for (; j + 8 <= deg; j += 8) {       // 8 VMEM loads in flight
        unsigned u[8];
        float w[8];
#pragma unroll
        for (int q = 0; q < 8; ++q) {
            const uint4 rc = s_rec[j + q];
            w[q] = w_of(rc, ht);
            u[q] = *(const unsigned*)(ft8 + (size_t)rc.z * 512 + t * 4);
        }
#pragma unroll
        for (int q = 0; q < 8; ++q) {
            z += w[q];
            const f32x2 lo = e4m3x2_to_f32<false>(u[q]), hi = e4m3x2_to_f32<true>(u[q]);
            acc.x += w[q] * lo[0]; acc.y += w[q] * lo[1];
            acc.z += w[q] * hi[0]; acc.w += w[q] * hi[1];
        }
    }
    for (; j < deg; ++j) {
        const uint4 rc = s_rec[j];
        const float w = w_of(rc, ht);
        z += w;
        const unsigned u = *(const unsigned*)(ft8 + (size_t)rc.z * 512 + t * 4);
        const f32x2 lo = e4m3x2_to_f32<false>(u);
        const f32x2 hi = e4m3x2_to_f32<true>(u);
        acc.x += w * lo[0]; acc.y += w * lo[1];
        acc.z += w * hi[0]; acc.w += w * hi[1];
    }
    const float rz = deg > 0 ? 1.f / z : 0.f;
    const uint2 ur = *(const uint2*)(res + (size_t)n * FDIM + t * 4);
    const float4 gb = ((const float4*)gat_bias)[t];
    union { bf16_t b[4]; uint2 u; } pk;
    pk.b[0] = (bf16_t)fmaxf(acc.x * rz + __uint_as_float(ur.x << 16) + gb.x, 0.f);
    pk.b[1] = (bf16_t)fmaxf(acc.y * rz + __uint_as_float(ur.x & 0xFFFF0000u) + gb.y, 0.f);
    pk.b[2] = (bf16_t)fmaxf(acc.z * rz + __uint_as_float(ur.y << 16) + gb.z, 0.f);
    pk.b[3] = (bf16_t)fmaxf(acc.w * rz + __uint_as_float(ur.y & 0xFFFF0000u) + gb.w, 0.f);
    *(uint2*)(x1 + (size_t)n * FDIM + t * 4) = pk.u;
}

extern "C" void kernel_launch(void* const* d_in, const int* in_sizes, int n_in,
                              void* d_out, int out_size, void* d_ws, size_t ws_size,
                              hipStream_t stream) {
    const float* h        = (const float*)d_in[0];
    const float* evals    = (const float*)d_in[1];
    const int*   src      = (const int*)d_in[2];
    const int*   dst      = (const int*)d_in[3];
    const float* W_fc     = (const float*)d_in[5];
    const float* attn_l   = (const float*)d_in[6];
    const float* attn_r   = (const float*)d_in[7];
    const float* W_fe     = (const float*)d_in[8];
    const float* attn_e   = (const float*)d_in[9];
    const float* W_res    = (const float*)d_in[10];
    const float* gat_bias = (const float*)d_in[11];
    const float* W_mha    = (const float*)d_in[12];
    const float* b_mha    = (const float*)d_in[13];
    const float* n1_g     = (const float*)d_in[14];
    const float* n1_b     = (const float*)d_in[15];
    const float* n2_g     = (const float*)d_in[16];
    const float* n2_b     = (const float*)d_in[17];
    const float* W1       = (const float*)d_in[18];
    const float* b1       = (const float*)d_in[19];
    const float* W2       = (const float*)d_in[20];
    const float* b2       = (const float*)d_in[21];

    char* ws = (char*)d_ws;
    unsigned char* ft8 = (unsigned char*)(ws + 0);   // 16MB  N x 512 fp8
    bf16_t* res     = (bf16_t*)(ws + 16777216ull);   // 32MB  N x 512
    bf16_t* x1      = (bf16_t*)(ws + 50331648ull);   // 32MB  N x 512
    uint4*  csr     = (uint4*) (ws + 83886080ull);   // 32MB  N x CAP x 16B packed
    bf16_t* hb      = (bf16_t*)(ws + 134217728ull);  // 8MB   N x 128
    bf16_t* Wfc_p   = (bf16_t*)(ws + 142606336ull);  // 128KB
    bf16_t* Wres_p  = (bf16_t*)(ws + 142737408ull);  // 128KB
    bf16_t* Wmha_p  = (bf16_t*)(ws + 142868480ull);  // 128KB
    bf16_t* W1_p    = (bf16_t*)(ws + 142999552ull);  // 512KB
    bf16_t* W2_p    = (bf16_t*)(ws + 143523840ull);  // 512KB
    float*  el      = (float*) (ws + 144048128ull);  // 512KB
    float*  er      = (float*) (ws + 144572416ull);  // 512KB
    float*  ce      = (float*) (ws + 145096704ull);  // 16B
    int*    cursor  = (int*)   (ws + 145096768ull);  // 128KB

    if (ws_size < 146000000ull) return;

    (void)hipMemsetAsync(cursor, 0, 131072, stream);

    prep_kernel<<<4449, 256, 0, stream>>>(h, hb, W_fc, Wfc_p, W_res, Wres_p,
                                          W_mha, Wmha_p, W1, W1_p, W2, W2_p,
                                          W_fe, attn_e, ce);
    gemm_ftres<<<dim3(4, 256), 256, 0, stream>>>(hb, Wfc_p, Wres_p, attn_l, attn_r, ft8, el, er, res);
    edge_build<<<E_EDGES / 256, 256, 0, stream>>>(evals, src, dst, el, er, ce, cursor, csr);
    aggregate_kernel<<<N_NODES, 128, 0, stream>>>(ft8, res, cursor, csr, gat_bias, x1);
    ffn_mega<<<256, 512, 0, stream>>>(x1, Wmha_p, b_mha, h, n1_g, n1_b,
                                      W1_p, b1, W2_p, b2, n2_g, n2_b, (float*)d_out);
}